// Round 8
// baseline (1051.805 us; speedup 1.0000x reference)
//
#include <hip/hip_runtime.h>

// LSTM_26912265077001: 2-layer LSTM (H=51, IN=1), T=512, B=1024, fp32.
//
// V9: defeat fragment REMATERIALIZATION.
// V8 post-mortem: waves_per_eu(2,2) changed nothing (VGPR=128, dur flat).
// Revised theory: the allocator CHOOSES 128 regs because the B-fragments
// are rebuildable (global load -> cvt -> pack of known values); the
// scheduler sinks those chains into the K-loop and rebuilds the weights
// EVERY iteration. Matches all counters: FETCH tiny (reloads are L1/L2
// hits), MfmaUtil 6.3% (360 of 4600 cy/iter), VALUBusy ~19% (cvt chains),
// rest = reload latency at 2 waves/SIMD.
// Fix:
//  (1) prep kernel pre-packs all B-fragments (hi/lo split done once) into
//      __device__ g_pack in the exact per-thread bf16x8 layout + fused
//      biases -> main-kernel setup is pure 16-B loads, nothing to remat.
//  (2) every fragment passes through asm volatile("" : "+v") -> value is
//      OPAQUE: cannot be recomputed, must stay register-resident.
// Everything else (MFMA schedule, E-steps, barriers, term order) is
// byte-identical to V8.
//
// Design recap (V5..V8, m89-verified MFMA maps):
//  - NB=16 batches/block, 64 blocks, 8 waves: waves 0-3 L1 (j-groups),
//    waves 4-7 L2. Gate-aligned B tiles: lane (m,ch) reg r ends with the
//    full (i,f,g,o) quad for (batch 4ch+r, unit jg*16+m) -> elementwise
//    fully in registers.
//  - A operand [h1(0..50) | x(51) | 0 | h2(64..114) | 0] bf16 hi/lo,
//    parity double-buffered. L1 K=64 (2 ksteps), L2 K=128 (4 ksteps).
//  - 3-term split product (AhBl + AlBh + AhBh), 1 barrier/iter.
//  - Pipeline: it: L1->h1[it] (it<Ts); L2->h2[it-1] (1<=it<=Ts);
//    y[it-2] (it>=2); loop to Ts+1 to drain.

#define Hs    51
#define Ts    512
#define Bs    1024
#define NB    16
#define NT    512
#define SA    136        // A row stride in ushorts (272B, 16B-aligned)
#define XCOL  51
#define H2COL 64

typedef __attribute__((ext_vector_type(8))) short bf16x8;
typedef __attribute__((ext_vector_type(4))) float f32x4;
typedef __attribute__((ext_vector_type(4))) int   i32x4;
typedef unsigned short u16;

__device__ __forceinline__ float sig_(float x)  { return 1.0f / (1.0f + __expf(-x)); }
__device__ __forceinline__ float tanh_(float x) { float e = __expf(2.0f * x); return 1.0f - 2.0f / (e + 1.0f); }
__device__ __forceinline__ u16 bfh_(float x) {   // fp32 -> bf16 (RNE)
    unsigned u = __float_as_uint(x);
    return (u16)((u + 0x7FFFu + ((u >> 16) & 1u)) >> 16);
}
__device__ __forceinline__ float bff_(u16 h) { return __uint_as_float(((unsigned)h) << 16); }

struct FragHL { bf16x8 h; bf16x8 l; };

// B1 fragment: row of [W_hh1 | W_ih1] at K-step ks, chunk ch.
__device__ __forceinline__ FragHL mkB1(const float* __restrict__ Whh1,
                                       const float* __restrict__ Wih1,
                                       int row, bool rv, int ks, int ch) {
    bf16x8 h = {0,0,0,0,0,0,0,0}, l = {0,0,0,0,0,0,0,0};
    #pragma unroll
    for (int j = 0; j < 8; ++j) {
        const int k = ks * 32 + ch * 8 + j;
        float v = 0.f;
        if (rv) {
            if (k < Hs)         v = Whh1[row * Hs + k];
            else if (k == XCOL) v = Wih1[row];
        }
        u16 hh = bfh_(v);
        h[j] = (short)hh;
        l[j] = (short)bfh_(v - bff_(hh));
    }
    FragHL r; r.h = h; r.l = l; return r;
}

// B2 fragment: row of [W_ih2 | 0 | W_hh2 | 0] at K-step ks, chunk ch.
__device__ __forceinline__ FragHL mkB2(const float* __restrict__ Wih2,
                                       const float* __restrict__ Whh2,
                                       int row, bool rv, int ks, int ch) {
    bf16x8 h = {0,0,0,0,0,0,0,0}, l = {0,0,0,0,0,0,0,0};
    #pragma unroll
    for (int j = 0; j < 8; ++j) {
        const int k = ks * 32 + ch * 8 + j;
        float v = 0.f;
        if (rv) {
            if (k < Hs)                              v = Wih2[row * Hs + k];
            else if (k >= H2COL && k < H2COL + Hs)   v = Whh2[row * Hs + (k - H2COL)];
        }
        u16 hh = bfh_(v);
        h[j] = (short)hh;
        l[j] = (short)bfh_(v - bff_(hh));
    }
    FragHL r; r.h = h; r.l = l; return r;
}

// ---- packed weight store: [tid][32 frag slots][8 u16] + fused biases ----
__device__ __align__(16) u16   g_pack[NT * 32 * 8];   // 256 KB
__device__ __align__(16) float g_bias[NT * 4];

__global__ __launch_bounds__(NT) void prep_kernel(
    const float* __restrict__ W_ih1, const float* __restrict__ W_hh1,
    const float* __restrict__ b_ih1, const float* __restrict__ b_hh1,
    const float* __restrict__ W_ih2, const float* __restrict__ W_hh2,
    const float* __restrict__ b_ih2, const float* __restrict__ b_hh2)
{
    const int tid  = threadIdx.x;
    const int lane = tid & 63;
    const int wv   = tid >> 6;
    const int role = wv >> 2;
    const int jg   = wv & 3;
    const int m    = lane & 15;
    const int ch   = lane >> 4;
    const int jrow = jg * 16 + m;
    const bool rv  = jrow < Hs;
    const int nks  = role ? 4 : 2;
    u16* base = &g_pack[tid * 256];

    for (int g = 0; g < 4; ++g) {
        const int row = g * Hs + jrow;
        g_bias[tid * 4 + g] = rv ? (role ? (b_ih2[row] + b_hh2[row])
                                         : (b_ih1[row] + b_hh1[row]))
                                 : 0.f;
        for (int s = 0; s < nks; ++s) {
            FragHL f = role ? mkB2(W_ih2, W_hh2, row, rv, s, ch)
                            : mkB1(W_hh1, W_ih1, row, rv, s, ch);
            *(bf16x8*)(base + (g * (2 * nks) + 2 * s + 0) * 8) = f.h;
            *(bf16x8*)(base + (g * (2 * nks) + 2 * s + 1) * 8) = f.l;
        }
    }
}

// opaque fragment load: value cannot be rematerialized by the compiler
__device__ __forceinline__ bf16x8 ldfrag(const u16* p) {
    i32x4 v = *(const i32x4*)p;
    asm volatile("" : "+v"(v));
    union { i32x4 i; bf16x8 b; } u;
    u.i = v;
    return u.b;
}

// 3-term split-product accumulate, same term order as V5 (numerics identical)
#define MF(ACC, AFH, AFL, BH, BL)                                              \
    ACC = __builtin_amdgcn_mfma_f32_16x16x32_bf16(AFH, BL, ACC, 0, 0, 0);      \
    ACC = __builtin_amdgcn_mfma_f32_16x16x32_bf16(AFL, BH, ACC, 0, 0, 0);      \
    ACC = __builtin_amdgcn_mfma_f32_16x16x32_bf16(AFH, BH, ACC, 0, 0, 0);

__global__ __launch_bounds__(NT)
__attribute__((amdgpu_waves_per_eu(2, 2)))
void lstm2_kernel(
    const float* __restrict__ x,      // (T, B, 1)
    const float* __restrict__ W_lin,  // (1, 51)
    const float* __restrict__ b_lin,  // (1,)
    float* __restrict__ out)          // (B, T)
{
    __shared__ __align__(16) u16   Ah[2][NB * SA];
    __shared__ __align__(16) u16   Al[2][NB * SA];
    __shared__ __align__(16) float xs[Ts][NB];
    __shared__ __align__(16) float h2f[2][NB][68];
    __shared__ __align__(16) float wlin_s[64];
    __shared__ float blin_sh;

    const int tid  = threadIdx.x;
    const int lane = tid & 63;
    const int wv   = tid >> 6;         // 0..7
    const int role = wv >> 2;          // 0 = L1, 1 = L2
    const int jg   = wv & 3;
    const int m    = lane & 15;
    const int ch   = lane >> 4;
    const int bg0  = blockIdx.x * NB;
    const int  jrow = jg * 16 + m;     // unit index (valid < 51)
    const bool rv   = jrow < Hs;

    // ---- one-time init: zero / preload (NO staging writes yet) ----
    for (int i = tid; i < Ts * NB; i += NT) {
        int t = i >> 4, b = i & 15;
        xs[t][b] = x[t * Bs + bg0 + b];
    }
    for (int i = tid; i < 2 * NB * SA; i += NT) {
        ((u16*)Ah)[i] = 0;
        ((u16*)Al)[i] = 0;
    }
    for (int i = tid; i < 2 * NB * 68; i += NT) ((float*)h2f)[i] = 0.f;
    if (tid < 64) wlin_s[tid] = (tid < Hs) ? W_lin[tid] : 0.f;
    if (tid == 0) blin_sh = b_lin[0];
    __syncthreads();                   // zero-fill visible first (V7 race fix)

    if (tid < NB) {                    // x[0] into parity 1 (read at it=0)
        float xv = x[bg0 + tid];
        u16 hh = bfh_(xv);
        Ah[1][tid * SA + XCOL] = hh;
        Al[1][tid * SA + XCOL] = bfh_(xv - bff_(hh));
    }

    // ---- biases: opaque register load ----
    f32x4 bb4 = *(const f32x4*)&g_bias[tid * 4];
    asm volatile("" : "+v"(bb4));
    const float bbI = bb4.x, bbF = bb4.y, bbG = bb4.z, bbO = bb4.w;

    const u16* pk = &g_pack[tid * 256];

    float cc0 = 0.f, cc1 = 0.f, cc2 = 0.f, cc3 = 0.f;
    __syncthreads();                   // staging visible before iter 0

    if (role == 0) {
        // ======================= L1 path =======================
        // 16 opaque fragment loads (slots g*4 + s*2 + hl)
        bf16x8 bI0h = ldfrag(pk + (0*4 + 0)*8), bI0l = ldfrag(pk + (0*4 + 1)*8);
        bf16x8 bI1h = ldfrag(pk + (0*4 + 2)*8), bI1l = ldfrag(pk + (0*4 + 3)*8);
        bf16x8 bF0h = ldfrag(pk + (1*4 + 0)*8), bF0l = ldfrag(pk + (1*4 + 1)*8);
        bf16x8 bF1h = ldfrag(pk + (1*4 + 2)*8), bF1l = ldfrag(pk + (1*4 + 3)*8);
        bf16x8 bG0h = ldfrag(pk + (2*4 + 0)*8), bG0l = ldfrag(pk + (2*4 + 1)*8);
        bf16x8 bG1h = ldfrag(pk + (2*4 + 2)*8), bG1l = ldfrag(pk + (2*4 + 3)*8);
        bf16x8 bO0h = ldfrag(pk + (3*4 + 0)*8), bO0l = ldfrag(pk + (3*4 + 1)*8);
        bf16x8 bO1h = ldfrag(pk + (3*4 + 2)*8), bO1l = ldfrag(pk + (3*4 + 3)*8);

        for (int it = 0; it <= Ts + 1; ++it) {
            const int pR = (it - 1) & 1;
            const int pW = it & 1;
            if (it < Ts) {
                const u16* ph = &Ah[pR][m * SA + ch * 8];
                const u16* pl = &Al[pR][m * SA + ch * 8];
                bf16x8 A0h = *(const bf16x8*)(ph);
                bf16x8 A0l = *(const bf16x8*)(pl);
                bf16x8 A1h = *(const bf16x8*)(ph + 32);
                bf16x8 A1l = *(const bf16x8*)(pl + 32);
                f32x4 aI = {bbI, bbI, bbI, bbI};
                f32x4 aF = {bbF, bbF, bbF, bbF};
                f32x4 aG = {bbG, bbG, bbG, bbG};
                f32x4 aO = {bbO, bbO, bbO, bbO};
                MF(aI, A0h, A0l, bI0h, bI0l)  MF(aF, A0h, A0l, bF0h, bF0l)
                MF(aG, A0h, A0l, bG0h, bG0l)  MF(aO, A0h, A0l, bO0h, bO0l)
                MF(aI, A1h, A1l, bI1h, bI1l)  MF(aF, A1h, A1l, bF1h, bF1l)
                MF(aG, A1h, A1l, bG1h, bG1l)  MF(aO, A1h, A1l, bO1h, bO1l)
                #define E1STEP(RR, CC)                                         \
                {                                                              \
                    float iv = sig_ (aI[RR]);                                  \
                    float fv = sig_ (aF[RR]);                                  \
                    float gv = tanh_(aG[RR]);                                  \
                    float ov = sig_ (aO[RR]);                                  \
                    CC = fmaf(fv, CC, iv * gv);                                \
                    float hv = ov * tanh_(CC);                                 \
                    if (rv) {                                                  \
                        const int b = 4 * ch + RR;                             \
                        u16 hh = bfh_(hv);                                     \
                        Ah[pW][b * SA + jrow] = hh;                            \
                        Al[pW][b * SA + jrow] = bfh_(hv - bff_(hh));           \
                    }                                                          \
                }
                E1STEP(0, cc0) E1STEP(1, cc1) E1STEP(2, cc2) E1STEP(3, cc3)
                #undef E1STEP
            }
            // x[it+1] staging into parity pW (wave 0, 16 lanes)
            if (jg == 0 && lane < NB && (it + 1) < Ts) {
                float xv = xs[it + 1][lane];
                u16 hh = bfh_(xv);
                Ah[pW][lane * SA + XCOL] = hh;
                Al[pW][lane * SA + XCOL] = bfh_(xv - bff_(hh));
            }
            // y[it-2] = W_lin . h2[it-2] + b  (batch = 4*jg + ch)
            if (it >= 2) {
                const float* hp = &h2f[it & 1][4 * jg + ch][0];
                float s = wlin_s[m]      * hp[m]
                        + wlin_s[m + 16] * hp[m + 16]
                        + wlin_s[m + 32] * hp[m + 32]
                        + wlin_s[m + 48] * hp[m + 48];
                s += __shfl_xor(s, 1);
                s += __shfl_xor(s, 2);
                s += __shfl_xor(s, 4);
                s += __shfl_xor(s, 8);
                if (m == 0) out[(bg0 + 4 * jg + ch) * Ts + (it - 2)] = s + blin_sh;
            }
            __syncthreads();
        }
    } else {
        // ======================= L2 path =======================
        // 32 opaque fragment loads (slots g*8 + s*2 + hl)
        bf16x8 cI0h = ldfrag(pk + (0*8 + 0)*8), cI0l = ldfrag(pk + (0*8 + 1)*8);
        bf16x8 cI1h = ldfrag(pk + (0*8 + 2)*8), cI1l = ldfrag(pk + (0*8 + 3)*8);
        bf16x8 cI2h = ldfrag(pk + (0*8 + 4)*8), cI2l = ldfrag(pk + (0*8 + 5)*8);
        bf16x8 cI3h = ldfrag(pk + (0*8 + 6)*8), cI3l = ldfrag(pk + (0*8 + 7)*8);
        bf16x8 cF0h = ldfrag(pk + (1*8 + 0)*8), cF0l = ldfrag(pk + (1*8 + 1)*8);
        bf16x8 cF1h = ldfrag(pk + (1*8 + 2)*8), cF1l = ldfrag(pk + (1*8 + 3)*8);
        bf16x8 cF2h = ldfrag(pk + (1*8 + 4)*8), cF2l = ldfrag(pk + (1*8 + 5)*8);
        bf16x8 cF3h = ldfrag(pk + (1*8 + 6)*8), cF3l = ldfrag(pk + (1*8 + 7)*8);
        bf16x8 cG0h = ldfrag(pk + (2*8 + 0)*8), cG0l = ldfrag(pk + (2*8 + 1)*8);
        bf16x8 cG1h = ldfrag(pk + (2*8 + 2)*8), cG1l = ldfrag(pk + (2*8 + 3)*8);
        bf16x8 cG2h = ldfrag(pk + (2*8 + 4)*8), cG2l = ldfrag(pk + (2*8 + 5)*8);
        bf16x8 cG3h = ldfrag(pk + (2*8 + 6)*8), cG3l = ldfrag(pk + (2*8 + 7)*8);
        bf16x8 cO0h = ldfrag(pk + (3*8 + 0)*8), cO0l = ldfrag(pk + (3*8 + 1)*8);
        bf16x8 cO1h = ldfrag(pk + (3*8 + 2)*8), cO1l = ldfrag(pk + (3*8 + 3)*8);
        bf16x8 cO2h = ldfrag(pk + (3*8 + 4)*8), cO2l = ldfrag(pk + (3*8 + 5)*8);
        bf16x8 cO3h = ldfrag(pk + (3*8 + 6)*8), cO3l = ldfrag(pk + (3*8 + 7)*8);

        for (int it = 0; it <= Ts + 1; ++it) {
            const int pR = (it - 1) & 1;
            const int pW = it & 1;
            if (it >= 1 && it <= Ts) {
                const u16* ph = &Ah[pR][m * SA + ch * 8];
                const u16* pl = &Al[pR][m * SA + ch * 8];
                bf16x8 A0h = *(const bf16x8*)(ph);
                bf16x8 A0l = *(const bf16x8*)(pl);
                bf16x8 A1h = *(const bf16x8*)(ph + 32);
                bf16x8 A1l = *(const bf16x8*)(pl + 32);
                bf16x8 A2h = *(const bf16x8*)(ph + 64);
                bf16x8 A2l = *(const bf16x8*)(pl + 64);
                bf16x8 A3h = *(const bf16x8*)(ph + 96);
                bf16x8 A3l = *(const bf16x8*)(pl + 96);
                f32x4 aI = {bbI, bbI, bbI, bbI};
                f32x4 aF = {bbF, bbF, bbF, bbF};
                f32x4 aG = {bbG, bbG, bbG, bbG};
                f32x4 aO = {bbO, bbO, bbO, bbO};
                MF(aI, A0h, A0l, cI0h, cI0l)  MF(aF, A0h, A0l, cF0h, cF0l)
                MF(aG, A0h, A0l, cG0h, cG0l)  MF(aO, A0h, A0l, cO0h, cO0l)
                MF(aI, A1h, A1l, cI1h, cI1l)  MF(aF, A1h, A1l, cF1h, cF1l)
                MF(aG, A1h, A1l, cG1h, cG1l)  MF(aO, A1h, A1l, cO1h, cO1l)
                MF(aI, A2h, A2l, cI2h, cI2l)  MF(aF, A2h, A2l, cF2h, cF2l)
                MF(aG, A2h, A2l, cG2h, cG2l)  MF(aO, A2h, A2l, cO2h, cO2l)
                MF(aI, A3h, A3l, cI3h, cI3l)  MF(aF, A3h, A3l, cF3h, cF3l)
                MF(aG, A3h, A3l, cG3h, cG3l)  MF(aO, A3h, A3l, cO3h, cO3l)
                const int pE = (it - 1) & 1;     // h2f parity for h2[it-1]
                #define E2STEP(RR, CC)                                         \
                {                                                              \
                    float iv = sig_ (aI[RR]);                                  \
                    float fv = sig_ (aF[RR]);                                  \
                    float gv = tanh_(aG[RR]);                                  \
                    float ov = sig_ (aO[RR]);                                  \
                    CC = fmaf(fv, CC, iv * gv);                                \
                    float hv = ov * tanh_(CC);                                 \
                    if (rv) {                                                  \
                        const int b = 4 * ch + RR;                             \
                        u16 hh = bfh_(hv);                                     \
                        Ah[pW][b * SA + H2COL + jrow] = hh;                    \
                        Al[pW][b * SA + H2COL + jrow] = bfh_(hv - bff_(hh));   \
                        h2f[pE][b][jrow] = hv;                                 \
                    }                                                          \
                }
                E2STEP(0, cc0) E2STEP(1, cc1) E2STEP(2, cc2) E2STEP(3, cc3)
                #undef E2STEP
            }
            __syncthreads();
        }
    }
}

extern "C" void kernel_launch(void* const* d_in, const int* in_sizes, int n_in,
                              void* d_out, int out_size, void* d_ws, size_t ws_size,
                              hipStream_t stream) {
    const float* x     = (const float*)d_in[0];
    const float* W_ih1 = (const float*)d_in[1];
    const float* W_hh1 = (const float*)d_in[2];
    const float* b_ih1 = (const float*)d_in[3];
    const float* b_hh1 = (const float*)d_in[4];
    const float* W_ih2 = (const float*)d_in[5];
    const float* W_hh2 = (const float*)d_in[6];
    const float* b_ih2 = (const float*)d_in[7];
    const float* b_hh2 = (const float*)d_in[8];
    const float* W_lin = (const float*)d_in[9];
    const float* b_lin = (const float*)d_in[10];
    float* out = (float*)d_out;

    prep_kernel<<<1, NT, 0, stream>>>(W_ih1, W_hh1, b_ih1, b_hh1,
                                      W_ih2, W_hh2, b_ih2, b_hh2);
    lstm2_kernel<<<Bs / NB, NT, 0, stream>>>(x, W_lin, b_lin, out);
}